// Round 5
// baseline (354.825 us; speedup 1.0000x reference)
//
#include <hip/hip_runtime.h>
#include <math.h>

#define GRID 240

// ---------------- persistent device scratch ----------------
__device__ __align__(16) float g_G[64 * 16];     // (X^T X)^-1 per SRN channel
__device__ __align__(16) float g_Wp[64 * 240];   // srn weights [o][15 rows][16]
__device__ __align__(16) float g_w2p[9 * 2304 * 4];
__device__ __align__(16) float g_w3p[17 * 2304 * 4];
__device__ __align__(16) float g_w4p[8 * 4608 * 4];
__device__ float g_s1[64],  g_q1[64];
__device__ float g_s2[128], g_q2[128];
__device__ float g_s3[128], g_q3[128];
__device__ float g_s4[128], g_q4[128];
__device__ __align__(16) float g_h1[4 * 30 * 30 * 64];
__device__ __align__(16) float g_h2[4 * 14 * 14 * 4 * 128];
__device__ __align__(16) float g_h3[4 * 6 * 6 * 4 * 128];
__device__ __align__(16) float g_h4[4 * 16 * 128];
__device__ int g_cnt;   // barrier state (zero-init; invariant: 0 between barriers)
__device__ int g_gen;

// Device-wide generation barrier. Safe: LDS 62.9KB -> >=2 blocks/CU ->
// capacity 512 >= 240 grid, all blocks co-resident. Agent-scope atomics
// bypass the non-coherent per-XCD L2; __threadfence() does wb/inv.
__device__ __forceinline__ void gridbar() {
    __syncthreads();
    __threadfence();
    if (threadIdx.x == 0) {
        int gen = __hip_atomic_load(&g_gen, __ATOMIC_RELAXED, __HIP_MEMORY_SCOPE_AGENT);
        if (__hip_atomic_fetch_add(&g_cnt, 1, __ATOMIC_ACQ_REL, __HIP_MEMORY_SCOPE_AGENT)
            == (int)gridDim.x - 1) {
            __hip_atomic_store(&g_cnt, 0, __ATOMIC_RELAXED, __HIP_MEMORY_SCOPE_AGENT);
            __hip_atomic_store(&g_gen, gen + 1, __ATOMIC_RELEASE, __HIP_MEMORY_SCOPE_AGENT);
        } else {
            while (__hip_atomic_load(&g_gen, __ATOMIC_RELAXED, __HIP_MEMORY_SCOPE_AGENT) == gen)
                __builtin_amdgcn_s_sleep(2);
        }
    }
    __syncthreads();
    __threadfence();
}

extern "C" __global__ void __launch_bounds__(256)
k_fused(const float* __restrict__ x, const float* __restrict__ srn_w,
        const float* __restrict__ w2, const float* __restrict__ w3,
        const float* __restrict__ w4,
        const float* __restrict__ g1, const float* __restrict__ b1,
        const float* __restrict__ g2, const float* __restrict__ b2,
        const float* __restrict__ g3, const float* __restrict__ b3,
        const float* __restrict__ g4, const float* __restrict__ b4,
        const float* __restrict__ fcw, const float* __restrict__ fcb,
        float* __restrict__ out) {
    extern __shared__ __align__(16) float smem[];
    int bid = blockIdx.x, t = threadIdx.x;

    // ================= stage 0: repacks + Gram + zero stats =================
    {
        int gid = bid * 256 + t, gstride = GRID * 256;
        for (int i = gid; i < 14400; i += gstride) {
            int o = i / 225, j = i % 225, row = j / 15, col = j % 15;
            g_Wp[o * 240 + row * 16 + col] = srn_w[i];
        }
        for (int j = gid; j < 73728; j += gstride) {
            int c = j & 3, s4 = j >> 2;
            int sl = s4 % 36, tmp = s4 / 36, oc_l = tmp & 63, blk = tmp >> 6;
            int it = blk & 3, ocg = blk >> 2;
            int kw = sl % 3, icq = (sl / 3) & 3, kh = sl / 12;
            int ic = it * 16 + icq * 4 + c;
            g_w2p[j] = w2[((ocg * 64 + oc_l) * 64 + ic) * 9 + kh * 3 + kw];
        }
        for (int j = gid; j < 147456; j += gstride) {
            int c = j & 3, s4 = j >> 2;
            int sl = s4 % 36, tmp = s4 / 36, oc_l = tmp & 63, blk = tmp >> 6;
            int it = blk & 7, ocg = blk >> 3;
            int kw = sl % 3, icq = (sl / 3) & 3, kh = sl / 12;
            int ic = it * 16 + icq * 4 + c;
            g_w3p[j] = w3[((ocg * 64 + oc_l) * 128 + ic) * 9 + kh * 3 + kw];
        }
        for (int j = gid; j < 147456; j += gstride) {
            int c = j & 3, s4 = j >> 2;
            int sl = s4 % 72, tmp = s4 / 72, oc_l = tmp & 15, blkq = tmp >> 4;
            int icq = blkq & 3, ocg = blkq >> 2;
            int kw = sl % 3, icb = (sl / 3) & 7, kh = sl / 24;
            int ic = icq * 32 + icb * 4 + c;
            g_w4p[j] = w4[((ocg * 16 + oc_l) * 128 + ic) * 9 + kh * 3 + kw];
        }
        if (bid == 1 && t < 128) {
            if (t < 64) { g_s1[t] = 0.f; g_q1[t] = 0.f; }
            g_s2[t] = 0.f; g_q2[t] = 0.f;
            g_s3[t] = 0.f; g_q3[t] = 0.f;
            g_s4[t] = 0.f; g_q4[t] = 0.f;
        }
        if (bid == 0 && t < 64) {
            int o = t;
            const float* w = srn_w + o * 225;
            float c01 = 0, c02 = 0, c03 = 0, c11 = 0, c12 = 0, c13 = 0,
                  c22 = 0, c23 = 0, c33 = 0;
            for (int n = 0; n < 75; n++) {
                float w1 = w[n * 3 + 0], w2v = w[n * 3 + 1], w3v = w[n * 3 + 2];
                c01 += w1; c02 += w2v; c03 += w3v;
                c11 += w1 * w1; c12 += w1 * w2v; c13 += w1 * w3v;
                c22 += w2v * w2v; c23 += w2v * w3v; c33 += w3v * w3v;
            }
            float A[4][8];
            A[0][0] = 75.f; A[0][1] = c01; A[0][2] = c02; A[0][3] = c03;
            A[1][0] = c01;  A[1][1] = c11; A[1][2] = c12; A[1][3] = c13;
            A[2][0] = c02;  A[2][1] = c12; A[2][2] = c22; A[2][3] = c23;
            A[3][0] = c03;  A[3][1] = c13; A[3][2] = c23; A[3][3] = c33;
            for (int i = 0; i < 4; i++)
                for (int j = 0; j < 4; j++) A[i][4 + j] = (i == j) ? 1.f : 0.f;
            for (int p = 0; p < 4; p++) {
                float ip = 1.f / A[p][p];
                for (int j = 0; j < 8; j++) A[p][j] *= ip;
                for (int i = 0; i < 4; i++) if (i != p) {
                    float f = A[i][p];
                    for (int j = 0; j < 8; j++) A[i][j] -= f * A[p][j];
                }
            }
            for (int i = 0; i < 4; i++)
                for (int j = 0; j < 4; j++) g_G[o * 16 + i * 4 + j] = A[i][4 + j];
        }
    }
    gridbar();

    // ================= stage 1: SRN + avgpool2 + bn1 stats (240 blocks) =====
    {
        float* wl   = smem;            // [64][84] current-c weights
        float* gl   = smem + 5376;     // [64][20]
        float* xsm  = smem + 6656;     // [648]
        float* part = smem + 7304;     // [2*15*66]
        float* redS = smem + 9284;     // [256]
        float* redQ = smem + 9540;     // [256]
        int b = bid / 60, rem = bid % 60, r = rem >> 1, ch = rem & 1;

        float4 greg = ((const float4*)g_G)[t];
        float xr[3];
#pragma unroll
        for (int k = 0; k < 3; k++) {
            int i = t + k * 256;
            if (i < 648) {
                int c = i / 216, rm = i % 216, rr = rm / 36, col = rm % 36;
                int gc = ch * 30 + col; if (gc > 63) gc = 63;
                xr[k] = x[((b * 3 + c) * 64 + (2 * r + rr)) * 64 + gc];
            }
        }
        float4 wreg[5];
#pragma unroll
        for (int k = 0; k < 5; k++) {
            int idx = k * 256 + t;
            wreg[k] = ((const float4*)g_Wp)[(idx / 20) * 60 + 0 * 20 + (idx % 20)];
        }
        *(float4*)&gl[(t >> 2) * 20 + (t & 3) * 4] = greg;
#pragma unroll
        for (int k = 0; k < 3; k++) { int i = t + k * 256; if (i < 648) xsm[i] = xr[k]; }
#pragma unroll
        for (int k = 0; k < 5; k++) {
            int idx = k * 256 + t;
            *(float4*)&wl[(idx / 20) * 84 + (idx % 20) * 4] = wreg[k];
        }
        __syncthreads();

        int w = t >> 6, o = t & 63;
        int rw = w & 1, cq = w >> 1, base = cq * 16;

        float z1[16], z2[16], z3[16], s[16], q[16];
#pragma unroll
        for (int i = 0; i < 16; i++) { z1[i]=0; z2[i]=0; z3[i]=0; s[i]=0; q[i]=0; }

        for (int c = 0; c < 3; c++) {
            if (c < 2) {
#pragma unroll
                for (int k = 0; k < 5; k++) {
                    int idx = k * 256 + t;
                    wreg[k] = ((const float4*)g_Wp)[(idx / 20) * 60 + (c + 1) * 20 + (idx % 20)];
                }
            }
#pragma unroll
            for (int kh = 0; kh < 5; kh++) {
                float xv[20];
#pragma unroll
                for (int k = 0; k < 20; k++) xv[k] = xsm[(c * 6 + rw + kh) * 36 + base + k];
                float wf[16];
                const float* wp = &wl[o * 84 + kh * 16];
                *(float4*)&wf[0]  = *(const float4*)&wp[0];
                *(float4*)&wf[4]  = *(const float4*)&wp[4];
                *(float4*)&wf[8]  = *(const float4*)&wp[8];
                *(float4*)&wf[12] = *(const float4*)&wp[12];
#pragma unroll
                for (int kw = 0; kw < 5; kw++) {
                    float w1 = wf[kw * 3], w2v = wf[kw * 3 + 1], w3v = wf[kw * 3 + 2];
#pragma unroll
                    for (int i = 0; i < 16; i++) {
                        float v = xv[kw + i];
                        s[i] += v; q[i] += v * v;
                        z1[i] += w1 * v; z2[i] += w2v * v; z3[i] += w3v * v;
                    }
                }
            }
            if (c < 2) {
                __syncthreads();
#pragma unroll
                for (int k = 0; k < 5; k++) {
                    int idx = k * 256 + t;
                    *(float4*)&wl[(idx / 20) * 84 + (idx % 20) * 4] = wreg[k];
                }
                __syncthreads();
            }
        }

        float gm[16];
        {
            const float* gp = &gl[o * 20];
            *(float4*)&gm[0]  = *(const float4*)&gp[0];
            *(float4*)&gm[4]  = *(const float4*)&gp[4];
            *(float4*)&gm[8]  = *(const float4*)&gp[8];
            *(float4*)&gm[12] = *(const float4*)&gp[12];
        }
        const float C1 = 0.36787944117144233f;
        const float INV = 1.5819767068693265f;
#pragma unroll
        for (int pp = 0; pp < 8; pp++) {
            int pl = cq * 8 + pp;
            if (pl < 15) {
                float aa = 0.f;
#pragma unroll
                for (int e = 0; e < 2; e++) {
                    int i = 2 * pp + e;
                    float sum = s[i], sq = q[i];
                    float gg2 = (sq - sum * sum * (1.f / 75.f)) * (1.f / 74.f);
                    float zf[4] = { sum, z1[i], z2[i], z3[i] };
                    float qf = 0.f;
#pragma unroll
                    for (int f = 0; f < 4; f++) {
                        float acc = 0.f;
#pragma unroll
                        for (int h = 0; h < 4; h++) acc += gm[f * 4 + h] * zf[h];
                        qf += acc * zf[f];
                    }
                    float err = (sq - qf) / (75.f * gg2);
                    aa += (expf(-err) - C1) * INV - 0.5f;
                }
                part[(rw * 15 + pl) * 66 + o] = 0.25f * aa;
            }
        }
        __syncthreads();

        int j = t >> 6;
        float ps = 0.f, pq = 0.f;
        for (int pl = j; pl < 15; pl += 4) {
            float v = part[pl * 66 + o] + part[(15 + pl) * 66 + o];
            g_h1[((b * 30 + r) * 30 + ch * 15 + pl) * 64 + o] = v;
            ps += v; pq += v * v;
        }
        redS[t] = ps; redQ[t] = pq;
        __syncthreads();
        if (t < 64) {
            atomicAdd(&g_s1[t], redS[t] + redS[64 + t] + redS[128 + t] + redS[192 + t]);
            atomicAdd(&g_q1[t], redQ[t] + redQ[64 + t] + redQ[128 + t] + redQ[192 + t]);
        }
    }
    gridbar();

    // ================= stage 2: bn1 + conv2 + bn2 stats (224 blocks) ========
    if (bid < 224) {
        float* ws   = smem;            // [64][148]
        float* xs   = smem + 9472;     // [3*30*64]
        float* redS = smem + 15232;
        float* redQ = smem + 15488;
        int b = bid / 56, rem = bid % 56, oh = rem >> 1, ocg = rem & 1;
        int oc_l = t & 63, qtr = t >> 6, owb = qtr * 7;

        {
            int icb = (t & 15) * 4;
            float4 S = *(const float4*)&g_s1[icb], Q = *(const float4*)&g_q1[icb];
            float4 G4 = *(const float4*)&g1[icb], B4 = *(const float4*)&b1[icb];
            float scv[4], shv[4];
            float mm[4] = { S.x, S.y, S.z, S.w }, qq[4] = { Q.x, Q.y, Q.z, Q.w };
            float gg[4] = { G4.x, G4.y, G4.z, G4.w }, bb[4] = { B4.x, B4.y, B4.z, B4.w };
#pragma unroll
            for (int c = 0; c < 4; c++) {
                float m = mm[c] * (1.f / 3600.f);
                float v = qq[c] * (1.f / 3600.f) - m * m;
                scv[c] = gg[c] * rsqrtf(v + 1e-5f);
                shv[c] = bb[c] - m * scv[c];
            }
            const float4* src4 = (const float4*)(g_h1 + (b * 900 + oh * 30) * 64);
            float4 xr[6];
#pragma unroll
            for (int k = 0; k < 6; k++) { int i4 = t + k * 256; if (i4 < 1440) xr[k] = src4[i4]; }
            const float4* wsrc0 = (const float4*)g_w2p;
            float4 wreg[9];
#pragma unroll
            for (int k = 0; k < 9; k++) wreg[k] = wsrc0[(ocg * 4) * 2304 + k * 256 + t];
#pragma unroll
            for (int k = 0; k < 6; k++) {
                int i4 = t + k * 256;
                if (i4 < 1440) {
                    float4 v;
                    v.x = xr[k].x * scv[0] + shv[0]; v.y = xr[k].y * scv[1] + shv[1];
                    v.z = xr[k].z * scv[2] + shv[2]; v.w = xr[k].w * scv[3] + shv[3];
                    *(float4*)&xs[i4 * 4] = v;
                }
            }
#pragma unroll
            for (int k = 0; k < 9; k++) {
                int idx = k * 256 + t;
                *(float4*)&ws[(idx / 36) * 148 + (idx % 36) * 4] = wreg[k];
            }
        }
        __syncthreads();

        float acc[7] = {0, 0, 0, 0, 0, 0, 0};
        const float4* wsrc = (const float4*)g_w2p + (ocg * 4) * 2304;
        for (int it = 0; it < 4; ++it) {
            float4 wreg[9];
            if (it < 3) {
#pragma unroll
                for (int k = 0; k < 9; k++) wreg[k] = wsrc[(it + 1) * 2304 + k * 256 + t];
            }
#pragma unroll 1
            for (int icq = 0; icq < 4; icq++) {
                int xoff = it * 16 + icq * 4;
#pragma unroll
                for (int kh = 0; kh < 3; kh++) {
                    const float* wb = &ws[oc_l * 148 + (kh * 4 + icq) * 12];
                    float4 w0 = *(const float4*)&wb[0];
                    float4 w1 = *(const float4*)&wb[4];
                    float4 w2v = *(const float4*)&wb[8];
                    const float* xrow = &xs[(kh * 30 + owb) * 64 + xoff];
                    float4 x0 = *(const float4*)&xrow[0];
                    float4 x1 = *(const float4*)&xrow[64];
#pragma unroll
                    for (int i = 0; i < 7; i++) {
                        float4 x2 = *(const float4*)&xrow[(i + 2) * 64];
                        acc[i] += w0.x * x0.x + w0.y * x0.y + w0.z * x0.z + w0.w * x0.w
                                + w1.x * x1.x + w1.y * x1.y + w1.z * x1.z + w1.w * x1.w
                                + w2v.x * x2.x + w2v.y * x2.y + w2v.z * x2.z + w2v.w * x2.w;
                        x0 = x1; x1 = x2;
                    }
                }
            }
            if (it < 3) {
                __syncthreads();
#pragma unroll
                for (int k = 0; k < 9; k++) {
                    int idx = k * 256 + t;
                    *(float4*)&ws[(idx / 36) * 148 + (idx % 36) * 4] = wreg[k];
                }
                __syncthreads();
            }
        }
        int oc = ocg * 64 + oc_l;
        float ps = 0.f, pq = 0.f;
#pragma unroll
        for (int i = 0; i < 7; i++) {
            int ow = owb + i;
            g_h2[(((b * 14 + (oh >> 1)) * 14 + (ow >> 1)) * 4 + (oh & 1) * 2 + (ow & 1)) * 128 + oc] = acc[i];
            ps += acc[i]; pq += acc[i] * acc[i];
        }
        redS[t] = ps; redQ[t] = pq;
        __syncthreads();
        if (t < 64) {
            atomicAdd(&g_s2[ocg * 64 + t], redS[t] + redS[64 + t] + redS[128 + t] + redS[192 + t]);
            atomicAdd(&g_q2[ocg * 64 + t], redQ[t] + redQ[64 + t] + redQ[128 + t] + redQ[192 + t]);
        }
    }
    gridbar();

    // ================= stage 3: bn2+relu+pool + conv3 + bn3 stats (96) ======
    if (bid < 96) {
        float* ws   = smem;            // [64][148]
        float* xs   = smem + 9472;     // [3*14*128]
        float* redS = smem + 14848;
        float* redQ = smem + 15104;
        int b = bid / 24, rem = bid % 24, oh = rem >> 1, ocg = rem & 1;
        int oc_l = t & 63, qtr = t >> 6, owb = qtr * 3;

        {
            int icb = (t & 31) * 4;
            float4 S = *(const float4*)&g_s2[icb], Q = *(const float4*)&g_q2[icb];
            float4 G4 = *(const float4*)&g2[icb], B4 = *(const float4*)&b2[icb];
            float scv[4], shv[4];
            float mm[4] = { S.x, S.y, S.z, S.w }, qq[4] = { Q.x, Q.y, Q.z, Q.w };
            float gg[4] = { G4.x, G4.y, G4.z, G4.w }, bb[4] = { B4.x, B4.y, B4.z, B4.w };
#pragma unroll
            for (int c = 0; c < 4; c++) {
                float m = mm[c] * (1.f / 3136.f);
                float v = qq[c] * (1.f / 3136.f) - m * m;
                scv[c] = gg[c] * rsqrtf(v + 1e-5f);
                shv[c] = bb[c] - m * scv[c];
            }
            const float4* wsrc0 = (const float4*)g_w3p;
            float4 wreg[9];
#pragma unroll
            for (int k = 0; k < 9; k++) wreg[k] = wsrc0[(ocg * 8) * 2304 + k * 256 + t];
            float4 pa[6], pb[6], pc[6], pd[6];
#pragma unroll
            for (int k = 0; k < 6; k++) {
                int i4 = t + k * 256;
                if (i4 < 1344) {
                    int px = (i4 >> 5) % 14, rr = i4 / 448;
                    const float4* p0 = (const float4*)&g_h2[(((b * 14 + oh + rr) * 14 + px) * 4) * 128 + (i4 & 31) * 4];
                    pa[k] = p0[0]; pb[k] = p0[32]; pc[k] = p0[64]; pd[k] = p0[96];
                }
            }
#pragma unroll
            for (int k = 0; k < 9; k++) {
                int idx = k * 256 + t;
                *(float4*)&ws[(idx / 36) * 148 + (idx % 36) * 4] = wreg[k];
            }
#pragma unroll
            for (int k = 0; k < 6; k++) {
                int i4 = t + k * 256;
                if (i4 < 1344) {
                    float4 o4;
                    o4.x = 0.25f * (fmaxf(pa[k].x * scv[0] + shv[0], 0.f) + fmaxf(pb[k].x * scv[0] + shv[0], 0.f)
                                  + fmaxf(pc[k].x * scv[0] + shv[0], 0.f) + fmaxf(pd[k].x * scv[0] + shv[0], 0.f));
                    o4.y = 0.25f * (fmaxf(pa[k].y * scv[1] + shv[1], 0.f) + fmaxf(pb[k].y * scv[1] + shv[1], 0.f)
                                  + fmaxf(pc[k].y * scv[1] + shv[1], 0.f) + fmaxf(pd[k].y * scv[1] + shv[1], 0.f));
                    o4.z = 0.25f * (fmaxf(pa[k].z * scv[2] + shv[2], 0.f) + fmaxf(pb[k].z * scv[2] + shv[2], 0.f)
                                  + fmaxf(pc[k].z * scv[2] + shv[2], 0.f) + fmaxf(pd[k].z * scv[2] + shv[2], 0.f));
                    o4.w = 0.25f * (fmaxf(pa[k].w * scv[3] + shv[3], 0.f) + fmaxf(pb[k].w * scv[3] + shv[3], 0.f)
                                  + fmaxf(pc[k].w * scv[3] + shv[3], 0.f) + fmaxf(pd[k].w * scv[3] + shv[3], 0.f));
                    *(float4*)&xs[i4 * 4] = o4;
                }
            }
        }
        __syncthreads();

        float acc[3] = {0, 0, 0};
        const float4* wsrc = (const float4*)g_w3p + (ocg * 8) * 2304;
        for (int it = 0; it < 8; ++it) {
            float4 wreg[9];
            if (it < 7) {
#pragma unroll
                for (int k = 0; k < 9; k++) wreg[k] = wsrc[(it + 1) * 2304 + k * 256 + t];
            }
#pragma unroll 1
            for (int icq = 0; icq < 4; icq++) {
                int xoff = it * 16 + icq * 4;
#pragma unroll
                for (int kh = 0; kh < 3; kh++) {
                    const float* wb = &ws[oc_l * 148 + (kh * 4 + icq) * 12];
                    float4 w0 = *(const float4*)&wb[0];
                    float4 w1 = *(const float4*)&wb[4];
                    float4 w2v = *(const float4*)&wb[8];
                    const float* xrow = &xs[(kh * 14 + owb) * 128 + xoff];
                    float4 x0 = *(const float4*)&xrow[0];
                    float4 x1 = *(const float4*)&xrow[128];
#pragma unroll
                    for (int i = 0; i < 3; i++) {
                        float4 x2 = *(const float4*)&xrow[(i + 2) * 128];
                        acc[i] += w0.x * x0.x + w0.y * x0.y + w0.z * x0.z + w0.w * x0.w
                                + w1.x * x1.x + w1.y * x1.y + w1.z * x1.z + w1.w * x1.w
                                + w2v.x * x2.x + w2v.y * x2.y + w2v.z * x2.z + w2v.w * x2.w;
                        x0 = x1; x1 = x2;
                    }
                }
            }
            if (it < 7) {
                __syncthreads();
#pragma unroll
                for (int k = 0; k < 9; k++) {
                    int idx = k * 256 + t;
                    *(float4*)&ws[(idx / 36) * 148 + (idx % 36) * 4] = wreg[k];
                }
                __syncthreads();
            }
        }
        int oc = ocg * 64 + oc_l;
        float ps = 0.f, pq = 0.f;
#pragma unroll
        for (int i = 0; i < 3; i++) {
            int ow = owb + i;
            g_h3[(((b * 6 + (oh >> 1)) * 6 + (ow >> 1)) * 4 + (oh & 1) * 2 + (ow & 1)) * 128 + oc] = acc[i];
            ps += acc[i]; pq += acc[i] * acc[i];
        }
        redS[t] = ps; redQ[t] = pq;
        __syncthreads();
        if (t < 64) {
            atomicAdd(&g_s3[ocg * 64 + t], redS[t] + redS[64 + t] + redS[128 + t] + redS[192 + t]);
            atomicAdd(&g_q3[ocg * 64 + t], redQ[t] + redQ[64 + t] + redQ[128 + t] + redQ[192 + t]);
        }
    }
    gridbar();

    // ================= stage 4: bn3+relu+maxpool + conv4 + bn4 stats (128) ==
    if (bid < 128) {
        float* ws  = smem;             // [32][292] (half the oc-rows at a time)
        float* xs  = smem + 9344;      // [3*6*128]
        float* red = smem + 11648;     // [256]
        int b = bid / 32, rem = bid % 32, oh = rem / 8, ocg = rem % 8;
        int oc_l = t & 15, ow = (t >> 4) & 3, icq = t >> 6;

        {
            int icb = (t & 31) * 4;
            float4 S = *(const float4*)&g_s3[icb], Q = *(const float4*)&g_q3[icb];
            float4 G4 = *(const float4*)&g3[icb], B4 = *(const float4*)&b3[icb];
            float scv[4], shv[4];
            float mm[4] = { S.x, S.y, S.z, S.w }, qq[4] = { Q.x, Q.y, Q.z, Q.w };
            float gg[4] = { G4.x, G4.y, G4.z, G4.w }, bb[4] = { B4.x, B4.y, B4.z, B4.w };
#pragma unroll
            for (int c = 0; c < 4; c++) {
                float m = mm[c] * (1.f / 576.f);
                float v = qq[c] * (1.f / 576.f) - m * m;
                scv[c] = gg[c] * rsqrtf(v + 1e-5f);
                shv[c] = bb[c] - m * scv[c];
            }
            float4 pa[3], pb[3], pc[3], pd[3];
#pragma unroll
            for (int k = 0; k < 3; k++) {
                int i4 = t + k * 256;
                if (i4 < 576) {
                    int px = (i4 >> 5) % 6, rr = i4 / 192;
                    const float4* p0 = (const float4*)&g_h3[(((b * 6 + oh + rr) * 6 + px) * 4) * 128 + (i4 & 31) * 4];
                    pa[k] = p0[0]; pb[k] = p0[32]; pc[k] = p0[64]; pd[k] = p0[96];
                }
            }
#pragma unroll
            for (int k = 0; k < 3; k++) {
                int i4 = t + k * 256;
                if (i4 < 576) {
                    float4 o4;
                    o4.x = fmaxf(fmaxf(fmaxf(pa[k].x * scv[0] + shv[0], pb[k].x * scv[0] + shv[0]),
                                       fmaxf(pc[k].x * scv[0] + shv[0], pd[k].x * scv[0] + shv[0])), 0.f);
                    o4.y = fmaxf(fmaxf(fmaxf(pa[k].y * scv[1] + shv[1], pb[k].y * scv[1] + shv[1]),
                                       fmaxf(pc[k].y * scv[1] + shv[1], pd[k].y * scv[1] + shv[1])), 0.f);
                    o4.z = fmaxf(fmaxf(fmaxf(pa[k].z * scv[2] + shv[2], pb[k].z * scv[2] + shv[2]),
                                       fmaxf(pc[k].z * scv[2] + shv[2], pd[k].z * scv[2] + shv[2])), 0.f);
                    o4.w = fmaxf(fmaxf(fmaxf(pa[k].w * scv[3] + shv[3], pb[k].w * scv[3] + shv[3]),
                                       fmaxf(pc[k].w * scv[3] + shv[3], pd[k].w * scv[3] + shv[3])), 0.f);
                    *(float4*)&xs[i4 * 4] = o4;
                }
            }
        }

        float acc = 0.f;
        const float4* wsrc = (const float4*)g_w4p + ocg * 4608;
        for (int h = 0; h < 2; h++) {
            float4 wreg[9];
#pragma unroll
            for (int k = 0; k < 9; k++) wreg[k] = wsrc[h * 2304 + k * 256 + t];
            __syncthreads();   // protect prior ws reads (h=1) / xs write visibility (h=0)
#pragma unroll
            for (int k = 0; k < 9; k++) {
                int idx = k * 256 + t;
                *(float4*)&ws[(idx / 72) * 292 + (idx % 72) * 4] = wreg[k];
            }
            __syncthreads();
            if ((icq >> 1) == h) {
                const float* wbase = &ws[((icq & 1) * 16 + oc_l) * 292];
#pragma unroll 1
                for (int icbq = 0; icbq < 8; icbq++) {
#pragma unroll
                    for (int kh = 0; kh < 3; kh++) {
                        const float* wb = &wbase[(kh * 8 + icbq) * 12];
                        float4 w0 = *(const float4*)&wb[0];
                        float4 w1 = *(const float4*)&wb[4];
                        float4 w2v = *(const float4*)&wb[8];
                        float4 x0 = *(const float4*)&xs[(kh * 6 + ow) * 128 + icq * 32 + icbq * 4];
                        float4 x1 = *(const float4*)&xs[(kh * 6 + ow + 1) * 128 + icq * 32 + icbq * 4];
                        float4 x2 = *(const float4*)&xs[(kh * 6 + ow + 2) * 128 + icq * 32 + icbq * 4];
                        acc += w0.x * x0.x + w0.y * x0.y + w0.z * x0.z + w0.w * x0.w
                             + w1.x * x1.x + w1.y * x1.y + w1.z * x1.z + w1.w * x1.w
                             + w2v.x * x2.x + w2v.y * x2.y + w2v.z * x2.z + w2v.w * x2.w;
                    }
                }
            }
        }
        red[t] = acc;
        __syncthreads();
        if (t < 64) {
            float v = red[t] + red[t + 64] + red[t + 128] + red[t + 192];
            int oc = ocg * 16 + (t & 15);
            g_h4[((b * 4 + oh) * 4 + (t >> 4)) * 128 + oc] = v;
            float ps = v + __shfl_xor(v, 16);  ps += __shfl_xor(ps, 32);
            float pv = v * v;
            float pq = pv + __shfl_xor(pv, 16); pq += __shfl_xor(pq, 32);
            if (t < 16) { atomicAdd(&g_s4[ocg * 16 + t], ps); atomicAdd(&g_q4[ocg * 16 + t], pq); }
        }
    }
    gridbar();

    // ================= stage 5: bn4+relu+maxpool4 + FC (block 0) ============
    if (bid == 0) {
        float* sc = smem;          // [128]
        float* sh = smem + 128;    // [128]
        float* pooled = smem + 256; // [4][128]
        if (t < 128) {
            float m = g_s4[t] * (1.f / 64.f);
            float v = g_q4[t] * (1.f / 64.f) - m * m;
            float rs = rsqrtf(v + 1e-5f);
            sc[t] = g4[t] * rs; sh[t] = b4[t] - m * sc[t];
        }
        __syncthreads();
        for (int item = t; item < 512; item += 256) {
            int b = item >> 7, oc = item & 127;
            float s = sc[oc], h = sh[oc];
            float mx = 0.f;
#pragma unroll
            for (int k = 0; k < 16; k++) mx = fmaxf(mx, g_h4[(b * 16 + k) * 128 + oc] * s + h);
            pooled[b * 128 + oc] = mx;
        }
        __syncthreads();
        if (t < 20) {
            int b = t / 5, cls = t % 5;
            float acc = fcb[cls];
            const float* w = &fcw[cls * 128];
            for (int oc = 0; oc < 128; oc++) acc += pooled[b * 128 + oc] * w[oc];
            out[b * 5 + cls] = acc;
        }
    }
}

extern "C" void kernel_launch(void* const* d_in, const int* in_sizes, int n_in,
                              void* d_out, int out_size, void* d_ws, size_t ws_size,
                              hipStream_t stream) {
    (void)in_sizes; (void)n_in; (void)out_size; (void)d_ws; (void)ws_size;
    const float* x     = (const float*)d_in[0];
    const float* srn_w = (const float*)d_in[1];
    const float* w2    = (const float*)d_in[2];
    const float* w3    = (const float*)d_in[4];
    const float* w4    = (const float*)d_in[6];
    const float* g1 = (const float*)d_in[8];  const float* b1 = (const float*)d_in[9];
    const float* g2 = (const float*)d_in[10]; const float* b2 = (const float*)d_in[11];
    const float* g3 = (const float*)d_in[12]; const float* b3 = (const float*)d_in[13];
    const float* g4 = (const float*)d_in[14]; const float* b4 = (const float*)d_in[15];
    const float* fcw = (const float*)d_in[16]; const float* fcb = (const float*)d_in[17];
    float* out = (float*)d_out;

    // dyn LDS = conv2 stage max: 15744 floats = 62976 B (<64KB -> >=2 blocks/CU
    // capacity -> 240-block grid always fully resident -> gridbar is safe)
    k_fused<<<dim3(GRID), dim3(256), 62976, stream>>>(
        x, srn_w, w2, w3, w4, g1, b1, g2, b2, g3, b3, g4, b4, fcw, fcb, out);
}

// Round 6
// 111.196 us; speedup vs baseline: 3.1910x; 3.1910x over previous
//
#include <hip/hip_runtime.h>
#include <math.h>

// ---------------- persistent device scratch (weights only) ----------------
__device__ __align__(16) float g_w2p[9 * 2304 * 4];   // conv2 staging-order (+pad)
__device__ __align__(16) float g_w3p[17 * 2304 * 4];  // conv3 staging-order (+pad)
__device__ __align__(16) float g_w4p[8 * 4608 * 4];   // conv4 staging-order
__device__ __align__(16) float g_h1[4 * 30 * 30 * 64];     // [b][r][c][ic]
__device__ __align__(16) float g_h2[4 * 14 * 14 * 4 * 128]; // pool-pair layout
__device__ __align__(16) float g_h3[4 * 6 * 6 * 4 * 128];   // pool-pair layout
__device__ __align__(16) float g_h4[4 * 16 * 128];
// BN stats live in d_ws (zeroed by hipMemsetAsync each call):
//   [0:64)=s1 [64:128)=q1 [128:256)=s2 [256:384)=q2
//   [384:512)=s3 [512:640)=q3 [640:768)=s4 [768:896)=q4

// ---------------- SRN + avgpool2 + bn1 stats (+ w2 repack, + inline Gram) --
// grid 240 = (b, pooled row r, col-half); block 256 = 4 waves; lane = o.
__global__ __launch_bounds__(256) void k_srn(const float* __restrict__ x,
                                             const float* __restrict__ srn_w,
                                             const float* __restrict__ w2,
                                             float* __restrict__ stats) {
    __shared__ __align__(16) float wlds[64 * 244];   // [o][15 rows][16]
    __shared__ float xsm[648];
    __shared__ float part[2 * 15 * 66];
    __shared__ float redS[256], redQ[256];
    int bid = blockIdx.x, t = threadIdx.x;
    int b = bid / 60, rem = bid % 60, r = rem >> 1, ch = rem & 1;

    // ---- w2 repack for k_conv2 (grid-strided; consumed next kernel only)
    for (int j = bid * 256 + t; j < 73728; j += 240 * 256) {
        int c = j & 3, s4 = j >> 2;
        int sl = s4 % 36, tmp = s4 / 36, oc_l = tmp & 63, blk = tmp >> 6;
        int it = blk & 3, ocg = blk >> 2;
        int kw = sl % 3, icq = (sl / 3) & 3, kh = sl / 12;
        int ic = it * 16 + icq * 4 + c;
        g_w2p[j] = w2[((ocg * 64 + oc_l) * 64 + ic) * 9 + kh * 3 + kw];
    }

    // ---- stage RAW srn weights -> wlds layout [o*244 + (c*5+kh)*16 + kw*3+s]
    float4 wr[15];
#pragma unroll
    for (int k = 0; k < 15; k++) {
        int i4 = k * 256 + t;
        if (i4 < 3600) wr[k] = ((const float4*)srn_w)[i4];
    }
    float xr[3];
#pragma unroll
    for (int k = 0; k < 3; k++) {
        int i = t + k * 256;
        if (i < 648) {
            int c = i / 216, rm = i % 216, rr = rm / 36, col = rm % 36;
            int gc = ch * 30 + col; if (gc > 63) gc = 63;
            xr[k] = x[((b * 3 + c) * 64 + (2 * r + rr)) * 64 + gc];
        }
    }
#pragma unroll
    for (int k = 0; k < 15; k++) {
        int i4 = k * 256 + t;
        if (i4 < 3600) {
            float v[4] = { wr[k].x, wr[k].y, wr[k].z, wr[k].w };
#pragma unroll
            for (int e = 0; e < 4; e++) {
                int i = i4 * 4 + e, o = i / 225, j = i % 225;
                wlds[o * 244 + (j / 15) * 16 + (j % 15)] = v[e];
            }
        }
    }
#pragma unroll
    for (int k = 0; k < 3; k++) { int i = t + k * 256; if (i < 648) xsm[i] = xr[k]; }
    __syncthreads();

    int w = t >> 6, o = t & 63;
    int rw = w & 1, cq = w >> 1, base = cq * 16;

    float z1[16], z2[16], z3[16], s[16], q[16];
#pragma unroll
    for (int i = 0; i < 16; i++) { z1[i]=0; z2[i]=0; z3[i]=0; s[i]=0; q[i]=0; }

    for (int c = 0; c < 3; c++) {
#pragma unroll
        for (int kh = 0; kh < 5; kh++) {
            float xv[20];
#pragma unroll
            for (int k = 0; k < 20; k++) xv[k] = xsm[(c * 6 + rw + kh) * 36 + base + k];
            float wf[16];
            const float* wp = &wlds[o * 244 + (c * 5 + kh) * 16];
            *(float4*)&wf[0]  = *(const float4*)&wp[0];
            *(float4*)&wf[4]  = *(const float4*)&wp[4];
            *(float4*)&wf[8]  = *(const float4*)&wp[8];
            *(float4*)&wf[12] = *(const float4*)&wp[12];
#pragma unroll
            for (int kw = 0; kw < 5; kw++) {
                float w1 = wf[kw * 3], w2v = wf[kw * 3 + 1], w3v = wf[kw * 3 + 2];
#pragma unroll
                for (int i = 0; i < 16; i++) {
                    float v = xv[kw + i];
                    s[i] += v; q[i] += v * v;
                    z1[i] += w1 * v; z2[i] += w2v * v; z3[i] += w3v * v;
                }
            }
        }
    }

    // ---- per-lane Gram + 4x4 inverse (after main loop: no liveness overlap)
    float gm[16];
    {
        float c01=0,c02=0,c03=0,c11=0,c12=0,c13=0,c22=0,c23=0,c33=0;
#pragma unroll
        for (int row = 0; row < 15; row++) {
            float wf[16];
            const float* wp = &wlds[o * 244 + row * 16];
            *(float4*)&wf[0]  = *(const float4*)&wp[0];
            *(float4*)&wf[4]  = *(const float4*)&wp[4];
            *(float4*)&wf[8]  = *(const float4*)&wp[8];
            *(float4*)&wf[12] = *(const float4*)&wp[12];
#pragma unroll
            for (int kw = 0; kw < 5; kw++) {
                float w1 = wf[kw*3], w2v = wf[kw*3+1], w3v = wf[kw*3+2];
                c01 += w1; c02 += w2v; c03 += w3v;
                c11 += w1*w1; c12 += w1*w2v; c13 += w1*w3v;
                c22 += w2v*w2v; c23 += w2v*w3v; c33 += w3v*w3v;
            }
        }
        float A[4][8];
        A[0][0]=75.f; A[0][1]=c01; A[0][2]=c02; A[0][3]=c03;
        A[1][0]=c01;  A[1][1]=c11; A[1][2]=c12; A[1][3]=c13;
        A[2][0]=c02;  A[2][1]=c12; A[2][2]=c22; A[2][3]=c23;
        A[3][0]=c03;  A[3][1]=c13; A[3][2]=c23; A[3][3]=c33;
#pragma unroll
        for (int i = 0; i < 4; i++)
#pragma unroll
            for (int j = 0; j < 4; j++) A[i][4 + j] = (i == j) ? 1.f : 0.f;
#pragma unroll
        for (int p = 0; p < 4; p++) {
            float ip = 1.f / A[p][p];
#pragma unroll
            for (int j = 0; j < 8; j++) A[p][j] *= ip;
#pragma unroll
            for (int i = 0; i < 4; i++) if (i != p) {
                float f = A[i][p];
#pragma unroll
                for (int j = 0; j < 8; j++) A[i][j] -= f * A[p][j];
            }
        }
#pragma unroll
        for (int i = 0; i < 4; i++)
#pragma unroll
            for (int j = 0; j < 4; j++) gm[i * 4 + j] = A[i][4 + j];
    }

    const float C1 = 0.36787944117144233f;
    const float INV = 1.5819767068693265f;
#pragma unroll
    for (int pp = 0; pp < 8; pp++) {
        int pl = cq * 8 + pp;
        if (pl < 15) {
            float aa = 0.f;
#pragma unroll
            for (int e = 0; e < 2; e++) {
                int i = 2 * pp + e;
                float sum = s[i], sq = q[i];
                float gg2 = (sq - sum * sum * (1.f / 75.f)) * (1.f / 74.f);
                float zf[4] = { sum, z1[i], z2[i], z3[i] };
                float qf = 0.f;
#pragma unroll
                for (int f = 0; f < 4; f++) {
                    float acc = 0.f;
#pragma unroll
                    for (int h = 0; h < 4; h++) acc += gm[f * 4 + h] * zf[h];
                    qf += acc * zf[f];
                }
                float err = (sq - qf) / (75.f * gg2);
                aa += (expf(-err) - C1) * INV - 0.5f;
            }
            part[(rw * 15 + pl) * 66 + o] = 0.25f * aa;
        }
    }
    __syncthreads();

    int j = t >> 6;
    float ps = 0.f, pq = 0.f;
    for (int pl = j; pl < 15; pl += 4) {
        float v = part[pl * 66 + o] + part[(15 + pl) * 66 + o];
        g_h1[((b * 30 + r) * 30 + ch * 15 + pl) * 64 + o] = v;
        ps += v; pq += v * v;
    }
    redS[t] = ps; redQ[t] = pq;
    __syncthreads();
    if (t < 64) {
        atomicAdd(&stats[t],      redS[t] + redS[64 + t] + redS[128 + t] + redS[192 + t]);
        atomicAdd(&stats[64 + t], redQ[t] + redQ[64 + t] + redQ[128 + t] + redQ[192 + t]);
    }
}

// -------- bn1-apply + conv2 + bn2 stats (+ w3 repack) --------
// grid 224 = (b, oh28, ocg2); block 256 = oc_l(64) x qtr(4, 7 ow)
__global__ __launch_bounds__(256) void k_conv2(const float* __restrict__ w3,
                                               const float* __restrict__ g1,
                                               const float* __restrict__ b1,
                                               float* __restrict__ stats) {
    __shared__ __align__(16) float ws[64 * 148];
    __shared__ __align__(16) float xs[3 * 30 * 64];
    __shared__ float redS[256], redQ[256];
    int blk = blockIdx.x;
    int b = blk / 56, rem = blk % 56, oh = rem >> 1, ocg = rem & 1;
    int t = threadIdx.x;
    int oc_l = t & 63, qtr = t >> 6, owb = qtr * 7;

    // w3 repack for k_conv3 (grid-strided)
    for (int j = blk * 256 + t; j < 147456; j += 224 * 256) {
        int c = j & 3, s4 = j >> 2;
        int sl = s4 % 36, tmp = s4 / 36, oc2 = tmp & 63, bk = tmp >> 6;
        int it = bk & 7, og = bk >> 3;
        int kw = sl % 3, icq = (sl / 3) & 3, kh = sl / 12;
        int ic = it * 16 + icq * 4 + c;
        g_w3p[j] = w3[((og * 64 + oc2) * 128 + ic) * 9 + kh * 3 + kw];
    }

    {   // staging: bn1 scales + input + weight tile 0
        int icb = (t & 15) * 4;
        float4 S = *(const float4*)&stats[icb], Q = *(const float4*)&stats[64 + icb];
        float4 G4 = *(const float4*)&g1[icb], B4 = *(const float4*)&b1[icb];
        float scv[4], shv[4];
        float mm[4] = { S.x, S.y, S.z, S.w }, qq[4] = { Q.x, Q.y, Q.z, Q.w };
        float gg[4] = { G4.x, G4.y, G4.z, G4.w }, bb[4] = { B4.x, B4.y, B4.z, B4.w };
#pragma unroll
        for (int c = 0; c < 4; c++) {
            float m = mm[c] * (1.f / 3600.f);
            float v = qq[c] * (1.f / 3600.f) - m * m;
            scv[c] = gg[c] * rsqrtf(v + 1e-5f);
            shv[c] = bb[c] - m * scv[c];
        }
        const float4* src4 = (const float4*)(g_h1 + (b * 900 + oh * 30) * 64);
        float4 xr[6];
#pragma unroll
        for (int k = 0; k < 6; k++) { int i4 = t + k * 256; if (i4 < 1440) xr[k] = src4[i4]; }
        const float4* wsrc0 = (const float4*)g_w2p;
        float4 wreg[9];
#pragma unroll
        for (int k = 0; k < 9; k++) wreg[k] = wsrc0[(ocg * 4) * 2304 + k * 256 + t];
#pragma unroll
        for (int k = 0; k < 6; k++) {
            int i4 = t + k * 256;
            if (i4 < 1440) {
                float4 v;
                v.x = xr[k].x * scv[0] + shv[0]; v.y = xr[k].y * scv[1] + shv[1];
                v.z = xr[k].z * scv[2] + shv[2]; v.w = xr[k].w * scv[3] + shv[3];
                *(float4*)&xs[i4 * 4] = v;
            }
        }
#pragma unroll
        for (int k = 0; k < 9; k++) {
            int idx = k * 256 + t;
            *(float4*)&ws[(idx / 36) * 148 + (idx % 36) * 4] = wreg[k];
        }
    }
    __syncthreads();

    float acc[7] = {0, 0, 0, 0, 0, 0, 0};
    const float4* wsrc = (const float4*)g_w2p + (ocg * 4) * 2304;
    for (int it = 0; it < 4; ++it) {
        float4 wreg[9];
        if (it < 3) {
#pragma unroll
            for (int k = 0; k < 9; k++) wreg[k] = wsrc[(it + 1) * 2304 + k * 256 + t];
        }
#pragma unroll 1
        for (int icq = 0; icq < 4; icq++) {
            int xoff = it * 16 + icq * 4;
#pragma unroll
            for (int kh = 0; kh < 3; kh++) {
                const float* wb = &ws[oc_l * 148 + (kh * 4 + icq) * 12];
                float4 w0 = *(const float4*)&wb[0];
                float4 w1 = *(const float4*)&wb[4];
                float4 w2v = *(const float4*)&wb[8];
                const float* xrow = &xs[(kh * 30 + owb) * 64 + xoff];
                float4 x0 = *(const float4*)&xrow[0];
                float4 x1 = *(const float4*)&xrow[64];
#pragma unroll
                for (int i = 0; i < 7; i++) {
                    float4 x2 = *(const float4*)&xrow[(i + 2) * 64];
                    acc[i] += w0.x * x0.x + w0.y * x0.y + w0.z * x0.z + w0.w * x0.w
                            + w1.x * x1.x + w1.y * x1.y + w1.z * x1.z + w1.w * x1.w
                            + w2v.x * x2.x + w2v.y * x2.y + w2v.z * x2.z + w2v.w * x2.w;
                    x0 = x1; x1 = x2;
                }
            }
        }
        if (it < 3) {
            __syncthreads();
#pragma unroll
            for (int k = 0; k < 9; k++) {
                int idx = k * 256 + t;
                *(float4*)&ws[(idx / 36) * 148 + (idx % 36) * 4] = wreg[k];
            }
            __syncthreads();
        }
    }
    int oc = ocg * 64 + oc_l;
    float ps = 0.f, pq = 0.f;
#pragma unroll
    for (int i = 0; i < 7; i++) {
        int ow = owb + i;
        g_h2[(((b * 14 + (oh >> 1)) * 14 + (ow >> 1)) * 4 + (oh & 1) * 2 + (ow & 1)) * 128 + oc] = acc[i];
        ps += acc[i]; pq += acc[i] * acc[i];
    }
    redS[t] = ps; redQ[t] = pq;
    __syncthreads();
    if (t < 64) {
        atomicAdd(&stats[128 + ocg * 64 + t], redS[t] + redS[64 + t] + redS[128 + t] + redS[192 + t]);
        atomicAdd(&stats[256 + ocg * 64 + t], redQ[t] + redQ[64 + t] + redQ[128 + t] + redQ[192 + t]);
    }
}

// -------- bn2+relu+avgpool2 + conv3 + bn3 stats (+ w4 repack) --------
// grid 96 = (b, oh12, ocg2); block 256 = oc_l(64) x qtr(4, 3 ow)
__global__ __launch_bounds__(256) void k_conv3(const float* __restrict__ w4,
                                               const float* __restrict__ g2,
                                               const float* __restrict__ b2,
                                               float* __restrict__ stats) {
    __shared__ __align__(16) float ws[64 * 148];
    __shared__ __align__(16) float xs[3 * 14 * 128];
    __shared__ float redS[256], redQ[256];
    int blk = blockIdx.x;
    int b = blk / 24, rem = blk % 24, oh = rem >> 1, ocg = rem & 1;
    int t = threadIdx.x;
    int oc_l = t & 63, qtr = t >> 6, owb = qtr * 3;

    // w4 repack for k_conv4 (grid-strided, exactly 6 rounds)
    for (int j = blk * 256 + t; j < 147456; j += 96 * 256) {
        int c = j & 3, s4 = j >> 2;
        int sl = s4 % 72, tmp = s4 / 72, oc2 = tmp & 15, blkq = tmp >> 4;
        int icq = blkq & 3, og = blkq >> 2;
        int kw = sl % 3, icb2 = (sl / 3) & 7, kh = sl / 24;
        int ic = icq * 32 + icb2 * 4 + c;
        g_w4p[j] = w4[((og * 16 + oc2) * 128 + ic) * 9 + kh * 3 + kw];
    }

    {
        int icb = (t & 31) * 4;
        float4 S = *(const float4*)&stats[128 + icb], Q = *(const float4*)&stats[256 + icb];
        float4 G4 = *(const float4*)&g2[icb], B4 = *(const float4*)&b2[icb];
        float scv[4], shv[4];
        float mm[4] = { S.x, S.y, S.z, S.w }, qq[4] = { Q.x, Q.y, Q.z, Q.w };
        float gg[4] = { G4.x, G4.y, G4.z, G4.w }, bb[4] = { B4.x, B4.y, B4.z, B4.w };
#pragma unroll
        for (int c = 0; c < 4; c++) {
            float m = mm[c] * (1.f / 3136.f);
            float v = qq[c] * (1.f / 3136.f) - m * m;
            scv[c] = gg[c] * rsqrtf(v + 1e-5f);
            shv[c] = bb[c] - m * scv[c];
        }
        const float4* wsrc0 = (const float4*)g_w3p;
        float4 wreg[9];
#pragma unroll
        for (int k = 0; k < 9; k++) wreg[k] = wsrc0[(ocg * 8) * 2304 + k * 256 + t];
        float4 pa[6], pb[6], pc[6], pd[6];
#pragma unroll
        for (int k = 0; k < 6; k++) {
            int i4 = t + k * 256;
            if (i4 < 1344) {
                int px = (i4 >> 5) % 14, rr = i4 / 448;
                const float4* p0 = (const float4*)&g_h2[(((b * 14 + oh + rr) * 14 + px) * 4) * 128 + (i4 & 31) * 4];
                pa[k] = p0[0]; pb[k] = p0[32]; pc[k] = p0[64]; pd[k] = p0[96];
            }
        }
#pragma unroll
        for (int k = 0; k < 9; k++) {
            int idx = k * 256 + t;
            *(float4*)&ws[(idx / 36) * 148 + (idx % 36) * 4] = wreg[k];
        }
#pragma unroll
        for (int k = 0; k < 6; k++) {
            int i4 = t + k * 256;
            if (i4 < 1344) {
                float4 o4;
                o4.x = 0.25f * (fmaxf(pa[k].x * scv[0] + shv[0], 0.f) + fmaxf(pb[k].x * scv[0] + shv[0], 0.f)
                              + fmaxf(pc[k].x * scv[0] + shv[0], 0.f) + fmaxf(pd[k].x * scv[0] + shv[0], 0.f));
                o4.y = 0.25f * (fmaxf(pa[k].y * scv[1] + shv[1], 0.f) + fmaxf(pb[k].y * scv[1] + shv[1], 0.f)
                              + fmaxf(pc[k].y * scv[1] + shv[1], 0.f) + fmaxf(pd[k].y * scv[1] + shv[1], 0.f));
                o4.z = 0.25f * (fmaxf(pa[k].z * scv[2] + shv[2], 0.f) + fmaxf(pb[k].z * scv[2] + shv[2], 0.f)
                              + fmaxf(pc[k].z * scv[2] + shv[2], 0.f) + fmaxf(pd[k].z * scv[2] + shv[2], 0.f));
                o4.w = 0.25f * (fmaxf(pa[k].w * scv[3] + shv[3], 0.f) + fmaxf(pb[k].w * scv[3] + shv[3], 0.f)
                              + fmaxf(pc[k].w * scv[3] + shv[3], 0.f) + fmaxf(pd[k].w * scv[3] + shv[3], 0.f));
                *(float4*)&xs[i4 * 4] = o4;
            }
        }
    }
    __syncthreads();

    float acc[3] = {0, 0, 0};
    const float4* wsrc = (const float4*)g_w3p + (ocg * 8) * 2304;
    for (int it = 0; it < 8; ++it) {
        float4 wreg[9];
        if (it < 7) {
#pragma unroll
            for (int k = 0; k < 9; k++) wreg[k] = wsrc[(it + 1) * 2304 + k * 256 + t];
        }
#pragma unroll 1
        for (int icq = 0; icq < 4; icq++) {
            int xoff = it * 16 + icq * 4;
#pragma unroll
            for (int kh = 0; kh < 3; kh++) {
                const float* wb = &ws[oc_l * 148 + (kh * 4 + icq) * 12];
                float4 w0 = *(const float4*)&wb[0];
                float4 w1 = *(const float4*)&wb[4];
                float4 w2v = *(const float4*)&wb[8];
                const float* xrow = &xs[(kh * 14 + owb) * 128 + xoff];
                float4 x0 = *(const float4*)&xrow[0];
                float4 x1 = *(const float4*)&xrow[128];
#pragma unroll
                for (int i = 0; i < 3; i++) {
                    float4 x2 = *(const float4*)&xrow[(i + 2) * 128];
                    acc[i] += w0.x * x0.x + w0.y * x0.y + w0.z * x0.z + w0.w * x0.w
                            + w1.x * x1.x + w1.y * x1.y + w1.z * x1.z + w1.w * x1.w
                            + w2v.x * x2.x + w2v.y * x2.y + w2v.z * x2.z + w2v.w * x2.w;
                    x0 = x1; x1 = x2;
                }
            }
        }
        if (it < 7) {
            __syncthreads();
#pragma unroll
            for (int k = 0; k < 9; k++) {
                int idx = k * 256 + t;
                *(float4*)&ws[(idx / 36) * 148 + (idx % 36) * 4] = wreg[k];
            }
            __syncthreads();
        }
    }
    int oc = ocg * 64 + oc_l;
    float ps = 0.f, pq = 0.f;
#pragma unroll
    for (int i = 0; i < 3; i++) {
        int ow = owb + i;
        g_h3[(((b * 6 + (oh >> 1)) * 6 + (ow >> 1)) * 4 + (oh & 1) * 2 + (ow & 1)) * 128 + oc] = acc[i];
        ps += acc[i]; pq += acc[i] * acc[i];
    }
    redS[t] = ps; redQ[t] = pq;
    __syncthreads();
    if (t < 64) {
        atomicAdd(&stats[384 + ocg * 64 + t], redS[t] + redS[64 + t] + redS[128 + t] + redS[192 + t]);
        atomicAdd(&stats[512 + ocg * 64 + t], redQ[t] + redQ[64 + t] + redQ[128 + t] + redQ[192 + t]);
    }
}

// -------- bn3+relu+maxpool2 + conv4 + bn4 stats --------
// grid 128 = (b, oh4, ocg8); block 256 = oc_l(16) x ow(4) x icq(4=wave)
__global__ __launch_bounds__(256) void k_conv4(const float* __restrict__ g3,
                                               const float* __restrict__ b3,
                                               float* __restrict__ stats) {
    __shared__ __align__(16) float ws[64 * 292];
    __shared__ __align__(16) float xs[3 * 6 * 128];
    __shared__ float red[256];
    int blk = blockIdx.x;
    int b = blk / 32, rem = blk % 32, oh = rem / 8, ocg = rem % 8;
    int t = threadIdx.x;
    int oc_l = t & 15, ow = (t >> 4) & 3, icq = t >> 6;

    {
        int icb = (t & 31) * 4;
        float4 S = *(const float4*)&stats[384 + icb], Q = *(const float4*)&stats[512 + icb];
        float4 G4 = *(const float4*)&g3[icb], B4 = *(const float4*)&b3[icb];
        float scv[4], shv[4];
        float mm[4] = { S.x, S.y, S.z, S.w }, qq[4] = { Q.x, Q.y, Q.z, Q.w };
        float gg[4] = { G4.x, G4.y, G4.z, G4.w }, bb[4] = { B4.x, B4.y, B4.z, B4.w };
#pragma unroll
        for (int c = 0; c < 4; c++) {
            float m = mm[c] * (1.f / 576.f);
            float v = qq[c] * (1.f / 576.f) - m * m;
            scv[c] = gg[c] * rsqrtf(v + 1e-5f);
            shv[c] = bb[c] - m * scv[c];
        }
        const float4* wsrc = (const float4*)g_w4p + ocg * 4608;
        float4 wreg[18];
#pragma unroll
        for (int k = 0; k < 18; k++) wreg[k] = wsrc[k * 256 + t];
        float4 pa[3], pb[3], pc[3], pd[3];
#pragma unroll
        for (int k = 0; k < 3; k++) {
            int i4 = t + k * 256;
            if (i4 < 576) {
                int px = (i4 >> 5) % 6, rr = i4 / 192;
                const float4* p0 = (const float4*)&g_h3[(((b * 6 + oh + rr) * 6 + px) * 4) * 128 + (i4 & 31) * 4];
                pa[k] = p0[0]; pb[k] = p0[32]; pc[k] = p0[64]; pd[k] = p0[96];
            }
        }
#pragma unroll
        for (int k = 0; k < 18; k++) {
            int idx = k * 256 + t;
            *(float4*)&ws[(idx / 72) * 292 + (idx % 72) * 4] = wreg[k];
        }
#pragma unroll
        for (int k = 0; k < 3; k++) {
            int i4 = t + k * 256;
            if (i4 < 576) {
                float4 o4;
                o4.x = fmaxf(fmaxf(fmaxf(pa[k].x * scv[0] + shv[0], pb[k].x * scv[0] + shv[0]),
                                   fmaxf(pc[k].x * scv[0] + shv[0], pd[k].x * scv[0] + shv[0])), 0.f);
                o4.y = fmaxf(fmaxf(fmaxf(pa[k].y * scv[1] + shv[1], pb[k].y * scv[1] + shv[1]),
                                   fmaxf(pc[k].y * scv[1] + shv[1], pd[k].y * scv[1] + shv[1])), 0.f);
                o4.z = fmaxf(fmaxf(fmaxf(pa[k].z * scv[2] + shv[2], pb[k].z * scv[2] + shv[2]),
                                   fmaxf(pc[k].z * scv[2] + shv[2], pd[k].z * scv[2] + shv[2])), 0.f);
                o4.w = fmaxf(fmaxf(fmaxf(pa[k].w * scv[3] + shv[3], pb[k].w * scv[3] + shv[3]),
                                   fmaxf(pc[k].w * scv[3] + shv[3], pd[k].w * scv[3] + shv[3])), 0.f);
                *(float4*)&xs[i4 * 4] = o4;
            }
        }
    }
    __syncthreads();

    float acc = 0.f;
    const float* wbase = &ws[(icq * 16 + oc_l) * 292];
#pragma unroll 1
    for (int icbq = 0; icbq < 8; icbq++) {
#pragma unroll
        for (int kh = 0; kh < 3; kh++) {
            const float* wb = &wbase[(kh * 8 + icbq) * 12];
            float4 w0 = *(const float4*)&wb[0];
            float4 w1 = *(const float4*)&wb[4];
            float4 w2v = *(const float4*)&wb[8];
            float4 x0 = *(const float4*)&xs[(kh * 6 + ow) * 128 + icq * 32 + icbq * 4];
            float4 x1 = *(const float4*)&xs[(kh * 6 + ow + 1) * 128 + icq * 32 + icbq * 4];
            float4 x2 = *(const float4*)&xs[(kh * 6 + ow + 2) * 128 + icq * 32 + icbq * 4];
            acc += w0.x * x0.x + w0.y * x0.y + w0.z * x0.z + w0.w * x0.w
                 + w1.x * x1.x + w1.y * x1.y + w1.z * x1.z + w1.w * x1.w
                 + w2v.x * x2.x + w2v.y * x2.y + w2v.z * x2.z + w2v.w * x2.w;
        }
    }
    red[t] = acc;
    __syncthreads();
    if (t < 64) {
        float v = red[t] + red[t + 64] + red[t + 128] + red[t + 192];
        int oc = ocg * 16 + (t & 15);
        g_h4[((b * 4 + oh) * 4 + (t >> 4)) * 128 + oc] = v;
        float ps = v + __shfl_xor(v, 16);  ps += __shfl_xor(ps, 32);
        float pv = v * v;
        float pq = pv + __shfl_xor(pv, 16); pq += __shfl_xor(pq, 32);
        if (t < 16) {
            atomicAdd(&stats[640 + ocg * 16 + t], ps);
            atomicAdd(&stats[768 + ocg * 16 + t], pq);
        }
    }
}

// ------- bn4+relu+maxpool4 + FC -------
__global__ __launch_bounds__(256) void k_final(const float* __restrict__ g4,
                                               const float* __restrict__ b4,
                                               const float* __restrict__ fcw,
                                               const float* __restrict__ fcb,
                                               const float* __restrict__ stats,
                                               float* __restrict__ out) {
    __shared__ float sc[128], sh[128];
    __shared__ float pooled[4][128];
    int t = threadIdx.x;
    if (t < 128) {
        float m = stats[640 + t] * (1.f / 64.f);
        float v = stats[768 + t] * (1.f / 64.f) - m * m;
        float rs = rsqrtf(v + 1e-5f);
        sc[t] = g4[t] * rs; sh[t] = b4[t] - m * sc[t];
    }
    __syncthreads();
    for (int item = t; item < 512; item += 256) {
        int b = item >> 7, oc = item & 127;
        float s = sc[oc], h = sh[oc];
        float mx = 0.f;
#pragma unroll
        for (int k = 0; k < 16; k++) mx = fmaxf(mx, g_h4[(b * 16 + k) * 128 + oc] * s + h);
        pooled[b][oc] = mx;
    }
    __syncthreads();
    if (t < 20) {
        int b = t / 5, cls = t % 5;
        float acc = fcb[cls];
        const float* w = &fcw[cls * 128];
        for (int oc = 0; oc < 128; oc++) acc += pooled[b][oc] * w[oc];
        out[b * 5 + cls] = acc;
    }
}

extern "C" void kernel_launch(void* const* d_in, const int* in_sizes, int n_in,
                              void* d_out, int out_size, void* d_ws, size_t ws_size,
                              hipStream_t stream) {
    (void)in_sizes; (void)n_in; (void)out_size; (void)ws_size;
    const float* x     = (const float*)d_in[0];
    const float* srn_w = (const float*)d_in[1];
    const float* w2    = (const float*)d_in[2];
    const float* w3    = (const float*)d_in[4];
    const float* w4    = (const float*)d_in[6];
    const float* g1 = (const float*)d_in[8];  const float* b1 = (const float*)d_in[9];
    const float* g2 = (const float*)d_in[10]; const float* b2 = (const float*)d_in[11];
    const float* g3 = (const float*)d_in[12]; const float* b3 = (const float*)d_in[13];
    const float* g4 = (const float*)d_in[14]; const float* b4 = (const float*)d_in[15];
    const float* fcw = (const float*)d_in[16]; const float* fcb = (const float*)d_in[17];
    float* out = (float*)d_out;
    float* stats = (float*)d_ws;   // 896 floats of BN-stat accumulators

    hipMemsetAsync(d_ws, 0, 4096, stream);
    k_srn  <<<dim3(240), dim3(256), 0, stream>>>(x, srn_w, w2, stats);
    k_conv2<<<dim3(224), dim3(256), 0, stream>>>(w3, g1, b1, stats);
    k_conv3<<<dim3(96),  dim3(256), 0, stream>>>(w4, g2, b2, stats);
    k_conv4<<<dim3(128), dim3(256), 0, stream>>>(g3, b3, stats);
    k_final<<<dim3(1),   dim3(256), 0, stream>>>(g4, b4, fcw, fcb, stats, out);
}